// Round 18
// baseline (183.250 us; speedup 1.0000x reference)
//
#include <hip/hip_runtime.h>

// SimpleSAGE v6. v5 post-mortem: k_sage1 49us, occ 10.9%, HBM 4.6% ->
// latency-bound with a mapping pathology: grid-stride 2048 == 0 mod 256
// meant every wave's slots shared one shard index -> 48% of waves had zero
// work, the rest serialized 8 slots of dependent 256B gathers at 2 blocks/CU.
// v6: ONE slot per wave (16384 waves == CAP), launch_bounds(256,4) for
// 4 blocks/CU residency, gather ILP 4 -> 8. Everything else unchanged.

constexpr int NN  = 50000;
constexpr int NG  = 500;
constexpr int NPG = 100;
constexpr int NE  = 800000;   // % 64 == 0
constexpr int D   = 64;
constexpr int NSH = 64;       // shards (= lanes)
constexpr int SEG = 256;      // entries per shard
constexpr int CAP = NSH * SEG;  // 16384 slots (~8.5k used)
constexpr int CPAD = 16;      // 64B line per shard counter
constexpr int MAXDEG = 64;    // bucket capacity (mean deg 16, tail ~1e-20)

// ---- workspace layout ----
constexpr size_t OFF_AGG2  = 0;                                   // NG*D f32   (zeroed)
constexpr size_t OFF_BMP   = OFF_AGG2 + (size_t)NG * D * 4;       // 2048 u32   (zeroed)
constexpr size_t OFF_DEGC  = OFF_BMP + 2048 * 4;                  // CAP i32    (zeroed)
constexpr size_t OFF_CNTE  = OFF_DEGC + (size_t)CAP * 4;          // NSH*CPAD   (zeroed)
constexpr size_t OFF_CNTS  = OFF_CNTE + (size_t)NSH * CPAD * 4;   // NSH*CPAD   (zeroed)
constexpr size_t ZERO_BYTES = OFF_CNTS + (size_t)NSH * CPAD * 4 - OFF_AGG2;
constexpr size_t OFF_H1    = OFF_CNTS + (size_t)NSH * CPAD * 4;   // CAP*D f32  (write-once)
constexpr size_t OFF_SLOT  = OFF_H1 + (size_t)CAP * D * 4;        // NN i32     (frontier only)
constexpr size_t OFF_NLIST = OFF_SLOT + (size_t)NN * 4;           // CAP i32
constexpr size_t OFF_ELIST = OFF_NLIST + (size_t)CAP * 4;         // CAP int2
constexpr size_t OFF_BKT   = OFF_ELIST + (size_t)CAP * 8;         // CAP*MAXDEG i32

// Scan edges; arithmetic center test (cpos[d/100]==d%100). Matched lanes
// append (src,dst) to their lane's shard segment and OR src into the bitmap.
// First NG threads also set the center bits (folded k_init).
__global__ void k_mark(const int* __restrict__ src, const int* __restrict__ dst,
                       const int* __restrict__ cpos, unsigned int* __restrict__ bmp,
                       int2* __restrict__ elist, int* __restrict__ cntE) {
  int gid  = blockIdx.x * blockDim.x + threadIdx.x;
  if (gid < NG) {
    int c = gid * NPG + cpos[gid];
    atomicOr(&bmp[c >> 5], 1u << (c & 31));
  }
  int lane = threadIdx.x & 63;
  int wid  = gid >> 6;
  int nw   = (gridDim.x * blockDim.x) >> 6;
  for (int base = wid * 64; base < NE; base += nw * 64) {
    int e = base + lane;
    int d = dst[e];
    int g = d / NPG;
    bool m = (g * NPG + cpos[g] == d);
    if (m) {
      int s = src[e];
      atomicOr(&bmp[s >> 5], 1u << (s & 31));
      int idx = atomicAdd(&cntE[lane * CPAD], 1);
      if (idx < SEG) elist[lane * SEG + idx] = make_int2(s, d);
    }
  }
}

// Assign sharded compact slots to bitmap nodes.
__global__ void k_compact(const unsigned int* __restrict__ bmp, int* __restrict__ slot,
                          int* __restrict__ nodelist, int* __restrict__ cntS) {
  int v = blockIdx.x * blockDim.x + threadIdx.x;
  int lane = threadIdx.x & 63;
  if (v >= NN) return;
  if ((bmp[v >> 5] >> (v & 31)) & 1) {
    int idx = atomicAdd(&cntS[lane * CPAD], 1);
    if (idx < SEG) {
      int sl = lane * SEG + idx;
      slot[v] = sl;
      nodelist[sl] = v;
    }
  }
}

// Scan edges; bitmap filters frontier dsts; matched lanes append their
// src id (4B) to the dst-slot's bucket. No row atomics, no ballot loop.
__global__ void k_fill(const int* __restrict__ src, const int* __restrict__ dst,
                       const unsigned int* __restrict__ bmp, const int* __restrict__ slot,
                       int* __restrict__ bucket, int* __restrict__ degC) {
  int lane = threadIdx.x & 63;
  int wid  = (blockIdx.x * blockDim.x + threadIdx.x) >> 6;
  int nw   = (gridDim.x * blockDim.x) >> 6;
  for (int base = wid * 64; base < NE; base += nw * 64) {
    int e = base + lane;
    int d = dst[e];
    if ((bmp[d >> 5] >> (d & 31)) & 1) {
      int sl  = slot[d];
      int idx = atomicAdd(&degC[sl], 1);
      if (idx < MAXDEG) bucket[sl * MAXDEG + idx] = src[e];
    }
  }
}

// Fused: mean over bucket x-rows (8-way ILP gathers) + register GEMV.
// ONE slot per wave: wave w handles slot w; invalid waves retire instantly.
__global__ __launch_bounds__(256, 4)
void k_sage1(const float* __restrict__ x, const int* __restrict__ nodelist,
             const int* __restrict__ degC, const int* __restrict__ bucket,
             float* __restrict__ h1out,
             const float* __restrict__ Wl, const float* __restrict__ bl,
             const float* __restrict__ Wr, const int* __restrict__ cntS) {
  int tid  = threadIdx.x;
  int lane = tid & 63;
  int sl   = (blockIdx.x * blockDim.x + tid) >> 6;   // wave id == slot id
  if (sl >= CAP) return;
  int shard = sl >> 8, idx = sl & (SEG - 1);
  int nval = cntS[shard * CPAD];
  if (idx >= (nval > SEG ? SEG : nval)) return;      // invalid slot -> retire

  int v   = nodelist[sl];
  int deg = degC[sl];
  int n   = deg < MAXDEG ? deg : MAXDEG;
  int myid = bucket[sl * MAXDEG + lane];             // lane's bucket entry

  float a0 = 0.f, a1 = 0.f, a2 = 0.f, a3 = 0.f;
  float a4 = 0.f, a5 = 0.f, a6 = 0.f, a7 = 0.f;
  int i = 0;
  for (; i + 8 <= n; i += 8) {
    int s0 = __shfl(myid, i),     s1 = __shfl(myid, i + 1);
    int s2 = __shfl(myid, i + 2), s3 = __shfl(myid, i + 3);
    int s4 = __shfl(myid, i + 4), s5 = __shfl(myid, i + 5);
    int s6 = __shfl(myid, i + 6), s7 = __shfl(myid, i + 7);
    a0 += x[(size_t)s0 * D + lane];
    a1 += x[(size_t)s1 * D + lane];
    a2 += x[(size_t)s2 * D + lane];
    a3 += x[(size_t)s3 * D + lane];
    a4 += x[(size_t)s4 * D + lane];
    a5 += x[(size_t)s5 * D + lane];
    a6 += x[(size_t)s6 * D + lane];
    a7 += x[(size_t)s7 * D + lane];
  }
  for (; i < n; i++) {
    int s = __shfl(myid, i);
    a0 += x[(size_t)s * D + lane];
  }
  float dg = (float)deg;
  if (dg < 1.f) dg = 1.f;
  float m  = (((a0 + a1) + (a2 + a3)) + ((a4 + a5) + (a6 + a7))) / dg;
  float xv = x[(size_t)v * D + lane];

  // register GEMV: lane owns output row `lane` of Wl/Wr
  const float4* Wl4 = (const float4*)(Wl + (size_t)lane * D);
  const float4* Wr4 = (const float4*)(Wr + (size_t)lane * D);
  float h0 = 0.f, hh1 = 0.f, h2 = 0.f, h3 = 0.f;
#pragma unroll
  for (int k = 0; k < D; k += 4) {
    float4 wl = Wl4[k >> 2];
    float4 wr = Wr4[k >> 2];
    float mk0 = __shfl(m, k),     xk0 = __shfl(xv, k);
    float mk1 = __shfl(m, k + 1), xk1 = __shfl(xv, k + 1);
    float mk2 = __shfl(m, k + 2), xk2 = __shfl(xv, k + 2);
    float mk3 = __shfl(m, k + 3), xk3 = __shfl(xv, k + 3);
    h0  += wl.x * mk0 + wl.z * mk2;
    hh1 += wr.x * xk0 + wr.z * xk2;
    h2  += wl.y * mk1 + wl.w * mk3;
    h3  += wr.y * xk1 + wr.w * xk3;
  }
  float h = bl[lane] + ((h0 + h2) + (hh1 + h3));
  h1out[(size_t)sl * D + lane] = fmaxf(h, 0.f);
}

// Center-edge list: agg2[graph(dst)] += h1[slot(src)].
__global__ void k_agg1(const int2* __restrict__ elist, const int* __restrict__ slot,
                       const float* __restrict__ h1, float* __restrict__ agg2,
                       const int* __restrict__ cntE) {
  int lane = threadIdx.x & 63;
  int wid  = (blockIdx.x * blockDim.x + threadIdx.x) >> 6;
  int nw   = (gridDim.x * blockDim.x) >> 6;
  for (int t = wid; t < CAP; t += nw) {
    int shard = t >> 8, idx = t & (SEG - 1);
    int n = cntE[shard * CPAD];
    if (idx >= (n > SEG ? SEG : n)) continue;   // wave-uniform
    int2 ed = elist[t];
    int sl = slot[ed.x];
    int g  = ed.y / NPG;
    atomicAdd(&agg2[(size_t)g * D + lane], h1[(size_t)sl * D + lane]);
  }
}

__global__ void k_final(const float* __restrict__ h1, const float* __restrict__ agg2,
                        const int* __restrict__ degC, const int* __restrict__ slot,
                        const int* __restrict__ cpos, const float* __restrict__ Wl2,
                        const float* __restrict__ bl2, const float* __restrict__ Wr2,
                        const float* __restrict__ Wlin, const float* __restrict__ blin,
                        float* __restrict__ out) {
  int lane = threadIdx.x & 63;
  int g = (blockIdx.x * blockDim.x + threadIdx.x) >> 6;
  if (g >= NG) return;
  int c  = g * NPG + cpos[g];
  int sl = slot[c];
  float dg = (float)degC[sl];
  if (dg < 1.f) dg = 1.f;
  float m  = agg2[(size_t)g * D + lane] / dg;
  float hc = h1[(size_t)sl * D + lane];
  float h  = bl2[lane];
#pragma unroll
  for (int k = 0; k < D; k++) {
    h += Wl2[lane * D + k] * __shfl(m, k) + Wr2[lane * D + k] * __shfl(hc, k);
  }
  h = fmaxf(h, 0.f);
  float p = Wlin[lane] * h;
#pragma unroll
  for (int off = 32; off; off >>= 1) p += __shfl_down(p, off);
  if (lane == 0) out[g] = p + blin[0];
}

extern "C" void kernel_launch(void* const* d_in, const int* in_sizes, int n_in,
                              void* d_out, int out_size, void* d_ws, size_t ws_size,
                              hipStream_t stream) {
  const float* x    = (const float*)d_in[0];
  const int*   ei   = (const int*)d_in[1];
  const int*   srcI = ei;          // edge_index[0]
  const int*   dstI = ei + NE;     // edge_index[1]
  const int*   cpos = (const int*)d_in[3];
  const float* Wl1  = (const float*)d_in[4];
  const float* bl1  = (const float*)d_in[5];
  const float* Wr1  = (const float*)d_in[6];
  const float* Wl2  = (const float*)d_in[7];
  const float* bl2  = (const float*)d_in[8];
  const float* Wr2  = (const float*)d_in[9];
  const float* Wlin = (const float*)d_in[10];
  const float* blin = (const float*)d_in[11];
  float* out = (float*)d_out;

  char* ws = (char*)d_ws;
  float*        agg2 = (float*)(ws + OFF_AGG2);
  unsigned int* bmp  = (unsigned int*)(ws + OFF_BMP);
  int*          degC = (int*)(ws + OFF_DEGC);
  int*          cntE = (int*)(ws + OFF_CNTE);
  int*          cntS = (int*)(ws + OFF_CNTS);
  float*        h1   = (float*)(ws + OFF_H1);
  int*          slot = (int*)(ws + OFF_SLOT);
  int*          nlst = (int*)(ws + OFF_NLIST);
  int2*         elst = (int2*)(ws + OFF_ELIST);
  int*          bkt  = (int*)(ws + OFF_BKT);

  hipMemsetAsync(ws + OFF_AGG2, 0, ZERO_BYTES, stream);
  k_mark<<<2048, 256, 0, stream>>>(srcI, dstI, cpos, bmp, elst, cntE);
  k_compact<<<(NN + 255) / 256, 256, 0, stream>>>(bmp, slot, nlst, cntS);
  k_fill<<<2048, 256, 0, stream>>>(srcI, dstI, bmp, slot, bkt, degC);
  k_sage1<<<CAP / 4, 256, 0, stream>>>(x, nlst, degC, bkt, h1, Wl1, bl1, Wr1, cntS);
  k_agg1<<<256, 256, 0, stream>>>(elst, slot, h1, agg2, cntE);
  k_final<<<(NG * 64 + 255) / 256, 256, 0, stream>>>(h1, agg2, degC, slot, cpos,
                                                     Wl2, bl2, Wr2, Wlin, blin, out);
}